// Round 1
// baseline (135.899 us; speedup 1.0000x reference)
//
#include <hip/hip_runtime.h>
#include <hip/hip_bf16.h>
#include <cstdint>
#include <cstddef>

typedef short bf16x8 __attribute__((ext_vector_type(8)));
typedef float f32x4 __attribute__((ext_vector_type(4)));

#if __has_builtin(__builtin_amdgcn_exp2f)
#define EXP2F(x) __builtin_amdgcn_exp2f(x)
#else
#define EXP2F(x) exp2f(x)
#endif

// scale^2 * log2(e) folded into Q; ch=64 -> (1/8)*1.4426950408889634
#define QSCALE 0.18033688011112043f

__device__ __forceinline__ short f2bf(float f) {
  union { __hip_bfloat16 b; short s; } u;
  u.b = __float2bfloat16(f);
  return u.s;
}

__device__ __forceinline__ unsigned int packbf2(float a, float b) {
  union { unsigned short u[2]; unsigned int w; } x;
  x.u[0] = (unsigned short)f2bf(a);
  x.u[1] = (unsigned short)f2bf(b);
  return x.w;
}

// ---------------------------------------------------------------------------
// Prepass: Kt[bh][s][c] = bf16(K[c][s]);  Vb[bh][c][s] = bf16(V[c][s]).
// qkv layout: [bh][cc][t], cc: 0..63 Q, 64..127 K, 128..191 V.
// One block per (bh, 64-wide s tile). Coalesced reads; LDS transpose for K.
// ---------------------------------------------------------------------------
__global__ __launch_bounds__(256, 4) void qkv_prep_kernel(
    const float* __restrict__ qkv, short* __restrict__ Kt,
    short* __restrict__ Vb) {
  const int bh = blockIdx.x >> 5;
  const int s0 = (blockIdx.x & 31) << 6;
  const int tid = threadIdx.x;
  const int row = tid >> 2;   // 0..63
  const int part = tid & 3;   // 0..3  (16 columns each)
  __shared__ float lds[64 * 65];

  const size_t qb = (size_t)bh * (192 * 2048);

  // ---- K: load [c][s] tile coalesced into LDS ----
  {
    const float* src = qkv + qb + (size_t)(64 + row) * 2048 + s0 + part * 16;
#pragma unroll
    for (int k4 = 0; k4 < 4; ++k4) {
      float4 v = ((const float4*)src)[k4];
      float* p = &lds[row * 65 + part * 16 + k4 * 4];
      p[0] = v.x; p[1] = v.y; p[2] = v.z; p[3] = v.w;
    }
  }
  __syncthreads();
  // ---- transposed read -> Kt[s][c], coalesced 16B stores ----
  {
    bf16x8 o0, o1;
#pragma unroll
    for (int k = 0; k < 8; ++k) o0[k] = f2bf(lds[(part * 16 + k) * 65 + row]);
#pragma unroll
    for (int k = 0; k < 8; ++k) o1[k] = f2bf(lds[(part * 16 + 8 + k) * 65 + row]);
    short* dst = Kt + ((size_t)bh * 2048 + s0 + row) * 64 + part * 16;
    *(bf16x8*)dst = o0;
    *(bf16x8*)(dst + 8) = o1;
  }
  // ---- V: straight convert, both sides coalesced ----
  {
    const float* src = qkv + qb + (size_t)(128 + row) * 2048 + s0 + part * 16;
    float a[16];
#pragma unroll
    for (int k4 = 0; k4 < 4; ++k4) {
      float4 v = ((const float4*)src)[k4];
      a[k4 * 4 + 0] = v.x; a[k4 * 4 + 1] = v.y;
      a[k4 * 4 + 2] = v.z; a[k4 * 4 + 3] = v.w;
    }
    bf16x8 o0, o1;
#pragma unroll
    for (int k = 0; k < 8; ++k) { o0[k] = f2bf(a[k]); o1[k] = f2bf(a[8 + k]); }
    short* dst = Vb + ((size_t)bh * 64 + row) * 2048 + s0 + part * 16;
    *(bf16x8*)dst = o0;
    *(bf16x8*)(dst + 8) = o1;
  }
}

// ---------------------------------------------------------------------------
// Flash attention. 1024 blocks (64 bh x 16 t-tiles of 128), 2 waves/block.
// Wave owns 64 t (4 n-tiles of 16). s-chunks of 64.
// MFMA 16x16x32 bf16, verified layouts:
//   operands: [out-dim row = lane&15][k = (lane>>4)*8+j contiguous]
//   C/D: col = lane&15, row = (lane>>4)*4 + reg
// QK^T swapped: D rows = s, cols = t  -> softmax per-lane + shfl_xor(16,32).
// K/V tiles in LDS, XOR-swizzled (byte ^= (row&7)<<4) to kill 128B-row
// bank conflicts. P bounced via per-wave swizzled LDS buffer.
// ---------------------------------------------------------------------------
__global__ __launch_bounds__(128, 2) void attn64_kernel(
    const float* __restrict__ qkv, const short* __restrict__ Kt,
    const short* __restrict__ Vb, float* __restrict__ out) {
  const int bh = blockIdx.x >> 4;
  const int tblk = blockIdx.x & 15;
  const int tid = threadIdx.x;
  const int wv = tid >> 6;
  const int lane = tid & 63;
  const int lo = lane & 15;
  const int g = lane >> 4;
  const int t0 = tblk * 128 + wv * 64;

  __shared__ __align__(16) char smem[32768];
  char* const Kls = smem;                      // [64 s][128B] swizzled
  char* const Vls = smem + 8192;               // [64 c][128B] swizzled
  char* const Pls = smem + 16384 + wv * 8192;  // per-wave [64 t][128B] swizzled

  // ---- Q fragments, held in registers for the whole K loop ----
  const size_t qb = (size_t)bh * (192 * 2048);
  bf16x8 qf[4][2];
#pragma unroll
  for (int nt = 0; nt < 4; ++nt) {
    const int t = t0 + nt * 16 + lo;
#pragma unroll
    for (int ks = 0; ks < 2; ++ks) {
#pragma unroll
      for (int j = 0; j < 8; ++j) {
        const int c = ks * 32 + g * 8 + j;
        qf[nt][ks][j] = f2bf(qkv[qb + (size_t)c * 2048 + t] * QSCALE);
      }
    }
  }

  f32x4 acc[4][4];
#pragma unroll
  for (int ct = 0; ct < 4; ++ct)
#pragma unroll
    for (int nt = 0; nt < 4; ++nt) acc[ct][nt] = f32x4{0.f, 0.f, 0.f, 0.f};

  float mrun[4] = {-1e30f, -1e30f, -1e30f, -1e30f};
  float lsum[4] = {0.f, 0.f, 0.f, 0.f};

  // staging geometry: wave stages 32 rows of K and of V per chunk
  const int srow = wv * 32 + (lane >> 3);  // +q*8, q=0..3
  const int col8 = lane & 7;
  const short* kptr = Kt + (size_t)bh * (2048 * 64) + (size_t)srow * 64 + col8 * 8;
  const short* vptr = Vb + ((size_t)bh * 64 + srow) * 2048 + col8 * 8;
  const int sdst = srow * 128 + ((col8 * 16) ^ ((srow & 7) * 16));

  for (int ch = 0; ch < 32; ++ch) {
    const int s0 = ch * 64;
    __syncthreads();
    {
      bf16x8 kq[4], vq[4];
#pragma unroll
      for (int q = 0; q < 4; ++q) {
        kq[q] = *(const bf16x8*)(kptr + (size_t)(s0 + q * 8) * 64);
        vq[q] = *(const bf16x8*)(vptr + (size_t)(q * 8) * 2048 + s0);
      }
#pragma unroll
      for (int q = 0; q < 4; ++q) {
        *(bf16x8*)(Kls + sdst + q * 1024) = kq[q];
        *(bf16x8*)(Vls + sdst + q * 1024) = vq[q];
      }
    }
    __syncthreads();

    // ---- QK^T ----
    f32x4 lg[4][4];
#pragma unroll
    for (int mt = 0; mt < 4; ++mt) {
#pragma unroll
      for (int nt = 0; nt < 4; ++nt) lg[mt][nt] = f32x4{0.f, 0.f, 0.f, 0.f};
      const int sr = mt * 16 + lo;
#pragma unroll
      for (int ks = 0; ks < 2; ++ks) {
        const bf16x8 ka = *(const bf16x8*)(
            Kls + sr * 128 + ((ks * 64 + g * 16) ^ ((sr & 7) * 16)));
#pragma unroll
        for (int nt = 0; nt < 4; ++nt)
          lg[mt][nt] = __builtin_amdgcn_mfma_f32_16x16x32_bf16(
              ka, qf[nt][ks], lg[mt][nt], 0, 0, 0);
      }
    }

    // ---- online max (deferred rescale, THR = 8 in log2 domain) ----
#pragma unroll
    for (int nt = 0; nt < 4; ++nt) {
      float cm = fmaxf(fmaxf(lg[0][nt][0], lg[0][nt][1]),
                       fmaxf(lg[0][nt][2], lg[0][nt][3]));
#pragma unroll
      for (int mt = 1; mt < 4; ++mt)
        cm = fmaxf(cm, fmaxf(fmaxf(lg[mt][nt][0], lg[mt][nt][1]),
                             fmaxf(lg[mt][nt][2], lg[mt][nt][3])));
      cm = fmaxf(cm, __shfl_xor(cm, 16));
      cm = fmaxf(cm, __shfl_xor(cm, 32));
      if (!__all(cm <= mrun[nt] + 8.0f)) {
        const float nm = fmaxf(mrun[nt], cm);
        const float fac = EXP2F(mrun[nt] - nm);
        mrun[nt] = nm;
        lsum[nt] *= fac;
#pragma unroll
        for (int ct = 0; ct < 4; ++ct) acc[ct][nt] *= fac;
      }
    }

    // ---- P = exp2(lg - m); PV in two 32-s halves ----
#pragma unroll
    for (int sh = 0; sh < 2; ++sh) {
#pragma unroll
      for (int mh = 0; mh < 2; ++mh) {
        const int mt = sh * 2 + mh;
#pragma unroll
        for (int nt = 0; nt < 4; ++nt) {
          const int t = nt * 16 + lo;
          f32x4 p;
#pragma unroll
          for (int r = 0; r < 4; ++r) p[r] = EXP2F(lg[mt][nt][r] - mrun[nt]);
          lsum[nt] += (p[0] + p[1]) + (p[2] + p[3]);
          uint2 w;
          w.x = packbf2(p[0], p[1]);
          w.y = packbf2(p[2], p[3]);
          *(uint2*)(Pls + t * 128 + ((mh * 32 + g * 8) ^ ((t & 7) * 16))) = w;
        }
      }
      bf16x8 pb[4];
#pragma unroll
      for (int nt = 0; nt < 4; ++nt) {
        const int t = nt * 16 + lo;
        pb[nt] = *(const bf16x8*)(Pls + t * 128 + ((g * 16) ^ ((t & 7) * 16)));
      }
#pragma unroll
      for (int ct = 0; ct < 4; ++ct) {
        const int cr = ct * 16 + lo;
        const bf16x8 va = *(const bf16x8*)(
            Vls + cr * 128 + ((sh * 64 + g * 16) ^ ((cr & 7) * 16)));
#pragma unroll
        for (int nt = 0; nt < 4; ++nt)
          acc[ct][nt] = __builtin_amdgcn_mfma_f32_16x16x32_bf16(
              va, pb[nt], acc[ct][nt], 0, 0, 0);
      }
    }
  }

  // ---- epilogue: normalize + store ----
#pragma unroll
  for (int nt = 0; nt < 4; ++nt) {
    float s = lsum[nt];
    s += __shfl_xor(s, 16);
    s += __shfl_xor(s, 32);
    const float inv = 1.0f / s;
    const int t = t0 + nt * 16 + lo;
#pragma unroll
    for (int ct = 0; ct < 4; ++ct) {
#pragma unroll
      for (int r = 0; r < 4; ++r) {
        const int c = ct * 16 + g * 4 + r;
        out[((size_t)bh * 64 + c) * 2048 + t] = acc[ct][nt][r] * inv;
      }
    }
  }
}

extern "C" void kernel_launch(void* const* d_in, const int* in_sizes, int n_in,
                              void* d_out, int out_size, void* d_ws,
                              size_t ws_size, hipStream_t stream) {
  (void)in_sizes; (void)n_in; (void)out_size;
  const float* qkv = (const float*)d_in[0];
  float* out = (float*)d_out;
  const size_t kv_elems = (size_t)64 * 2048 * 64;
  if (ws_size < kv_elems * 2 * sizeof(short)) return;  // need 32 MB scratch
  short* Kt = (short*)d_ws;
  short* Vb = Kt + kv_elems;
  hipLaunchKernelGGL(qkv_prep_kernel, dim3(2048), dim3(256), 0, stream,
                     qkv, Kt, Vb);
  hipLaunchKernelGGL(attn64_kernel, dim3(1024), dim3(128), 0, stream,
                     qkv, Kt, Vb, out);
}

// Round 2
// 125.441 us; speedup vs baseline: 1.0834x; 1.0834x over previous
//
#include <hip/hip_runtime.h>
#include <hip/hip_bf16.h>
#include <cstdint>
#include <cstddef>

typedef short bf16x8 __attribute__((ext_vector_type(8)));
typedef float f32x4 __attribute__((ext_vector_type(4)));

#if __has_builtin(__builtin_amdgcn_exp2f)
#define EXP2F(x) __builtin_amdgcn_exp2f(x)
#else
#define EXP2F(x) exp2f(x)
#endif

// scale^2 * log2(e) folded into Q; ch=64 -> (1/8)*1.4426950408889634
#define QSCALE 0.18033688011112043f

__device__ __forceinline__ short f2bf(float f) {
  union { __hip_bfloat16 b; short s; } u;
  u.b = __float2bfloat16(f);
  return u.s;
}

__device__ __forceinline__ unsigned int packbf2(float a, float b) {
  union { unsigned short u[2]; unsigned int w; } x;
  x.u[0] = (unsigned short)f2bf(a);
  x.u[1] = (unsigned short)f2bf(b);
  return x.w;
}

// ---------------------------------------------------------------------------
// Prepass: Kt[bh][s][c] = bf16(K[c][s]);  Vb[bh][c][s] = bf16(V[c][s]).
// qkv layout: [bh][cc][t], cc: 0..63 Q, 64..127 K, 128..191 V.
// One block per (bh, 64-wide s tile). Coalesced reads; LDS transpose for K.
// ---------------------------------------------------------------------------
__global__ __launch_bounds__(256, 4) void qkv_prep_kernel(
    const float* __restrict__ qkv, short* __restrict__ Kt,
    short* __restrict__ Vb) {
  const int bh = blockIdx.x >> 5;
  const int s0 = (blockIdx.x & 31) << 6;
  const int tid = threadIdx.x;
  const int row = tid >> 2;   // 0..63
  const int part = tid & 3;   // 0..3  (16 columns each)
  __shared__ float lds[64 * 65];

  const size_t qb = (size_t)bh * (192 * 2048);

  // ---- K: load [c][s] tile coalesced into LDS ----
  {
    const float* src = qkv + qb + (size_t)(64 + row) * 2048 + s0 + part * 16;
#pragma unroll
    for (int k4 = 0; k4 < 4; ++k4) {
      float4 v = ((const float4*)src)[k4];
      float* p = &lds[row * 65 + part * 16 + k4 * 4];
      p[0] = v.x; p[1] = v.y; p[2] = v.z; p[3] = v.w;
    }
  }
  __syncthreads();
  // ---- transposed read -> Kt[s][c], coalesced 16B stores ----
  {
    bf16x8 o0, o1;
#pragma unroll
    for (int k = 0; k < 8; ++k) o0[k] = f2bf(lds[(part * 16 + k) * 65 + row]);
#pragma unroll
    for (int k = 0; k < 8; ++k) o1[k] = f2bf(lds[(part * 16 + 8 + k) * 65 + row]);
    short* dst = Kt + ((size_t)bh * 2048 + s0 + row) * 64 + part * 16;
    *(bf16x8*)dst = o0;
    *(bf16x8*)(dst + 8) = o1;
  }
  // ---- V: straight convert, both sides coalesced ----
  {
    const float* src = qkv + qb + (size_t)(128 + row) * 2048 + s0 + part * 16;
    float a[16];
#pragma unroll
    for (int k4 = 0; k4 < 4; ++k4) {
      float4 v = ((const float4*)src)[k4];
      a[k4 * 4 + 0] = v.x; a[k4 * 4 + 1] = v.y;
      a[k4 * 4 + 2] = v.z; a[k4 * 4 + 3] = v.w;
    }
    bf16x8 o0, o1;
#pragma unroll
    for (int k = 0; k < 8; ++k) { o0[k] = f2bf(a[k]); o1[k] = f2bf(a[8 + k]); }
    short* dst = Vb + ((size_t)bh * 64 + row) * 2048 + s0 + part * 16;
    *(bf16x8*)dst = o0;
    *(bf16x8*)(dst + 8) = o1;
  }
}

// ---------------------------------------------------------------------------
// Flash attention. 1024 blocks (64 bh x 16 t-tiles of 128), 4 waves/block.
// Wave owns 32 t (2 n-tiles of 16)  ->  4096 waves = 4/SIMD resident.
// s-chunks of 64, K/V tiles staged cooperatively by all 4 waves.
// MFMA 16x16x32 bf16, verified layouts:
//   operands: [out-dim row = lane&15][k = (lane>>4)*8+j contiguous]
//   C/D: col = lane&15, row = (lane>>4)*4 + reg
// QK^T swapped: D rows = s, cols = t  -> softmax per-lane + shfl_xor(16,32).
// K/V tiles in LDS, XOR-swizzled (byte ^= (row&7)*16) to kill 128B-row
// bank conflicts. P bounced via per-wave swizzled LDS buffer.
// ---------------------------------------------------------------------------
__global__ __launch_bounds__(256, 4) void attn32_kernel(
    const float* __restrict__ qkv, const short* __restrict__ Kt,
    const short* __restrict__ Vb, float* __restrict__ out) {
  const int bh = blockIdx.x >> 4;
  const int tblk = blockIdx.x & 15;
  const int tid = threadIdx.x;
  const int wv = tid >> 6;
  const int lane = tid & 63;
  const int lo = lane & 15;
  const int g = lane >> 4;
  const int t0 = tblk * 128 + wv * 32;

  __shared__ __align__(16) char smem[32768];
  char* const Kls = smem;                      // [64 s][128B] swizzled
  char* const Vls = smem + 8192;               // [64 c][128B] swizzled
  char* const Pls = smem + 16384 + wv * 4096;  // per-wave [32 t][128B] swizzled

  // ---- Q fragments, held in registers for the whole K loop ----
  const size_t qb = (size_t)bh * (192 * 2048);
  bf16x8 qf[2][2];
#pragma unroll
  for (int nt = 0; nt < 2; ++nt) {
    const int t = t0 + nt * 16 + lo;
#pragma unroll
    for (int ks = 0; ks < 2; ++ks) {
#pragma unroll
      for (int j = 0; j < 8; ++j) {
        const int c = ks * 32 + g * 8 + j;
        qf[nt][ks][j] = f2bf(qkv[qb + (size_t)c * 2048 + t] * QSCALE);
      }
    }
  }

  f32x4 acc[4][2];
#pragma unroll
  for (int ct = 0; ct < 4; ++ct)
#pragma unroll
    for (int nt = 0; nt < 2; ++nt) acc[ct][nt] = f32x4{0.f, 0.f, 0.f, 0.f};

  float mrun[2] = {-1e30f, -1e30f};
  float lsum[2] = {0.f, 0.f};

  // staging geometry: 256 threads stage 64 rows of K and of V per chunk
  // (two q-steps of 32 rows; 8 lanes x 16B cover one 128B row)
  const int srow = tid >> 3;   // 0..31
  const int col8 = tid & 7;    // 16B slot within row
  const short* kptr = Kt + (size_t)bh * (2048 * 64) + (size_t)srow * 64 + col8 * 8;
  const short* vptr = Vb + ((size_t)bh * 64 + srow) * 2048 + col8 * 8;
  // (srow+32)&7 == srow&7 so the swizzle term is q-invariant
  const int sdst = srow * 128 + ((col8 * 16) ^ ((srow & 7) * 16));

  for (int ch = 0; ch < 32; ++ch) {
    const int s0 = ch * 64;
    __syncthreads();
    {
      bf16x8 kq[2], vq[2];
#pragma unroll
      for (int q = 0; q < 2; ++q) {
        kq[q] = *(const bf16x8*)(kptr + (size_t)(s0 + q * 32) * 64);
        vq[q] = *(const bf16x8*)(vptr + (size_t)(q * 32) * 2048 + s0);
      }
#pragma unroll
      for (int q = 0; q < 2; ++q) {
        *(bf16x8*)(Kls + sdst + q * 4096) = kq[q];
        *(bf16x8*)(Vls + sdst + q * 4096) = vq[q];
      }
    }
    __syncthreads();

    // ---- QK^T ----
    f32x4 lg[4][2];
#pragma unroll
    for (int mt = 0; mt < 4; ++mt) {
#pragma unroll
      for (int nt = 0; nt < 2; ++nt) lg[mt][nt] = f32x4{0.f, 0.f, 0.f, 0.f};
      const int sr = mt * 16 + lo;
#pragma unroll
      for (int ks = 0; ks < 2; ++ks) {
        const bf16x8 ka = *(const bf16x8*)(
            Kls + sr * 128 + ((ks * 64 + g * 16) ^ ((sr & 7) * 16)));
#pragma unroll
        for (int nt = 0; nt < 2; ++nt)
          lg[mt][nt] = __builtin_amdgcn_mfma_f32_16x16x32_bf16(
              ka, qf[nt][ks], lg[mt][nt], 0, 0, 0);
      }
    }

    // ---- online max (deferred rescale, THR = 8 in log2 domain) ----
#pragma unroll
    for (int nt = 0; nt < 2; ++nt) {
      float cm = fmaxf(fmaxf(lg[0][nt][0], lg[0][nt][1]),
                       fmaxf(lg[0][nt][2], lg[0][nt][3]));
#pragma unroll
      for (int mt = 1; mt < 4; ++mt)
        cm = fmaxf(cm, fmaxf(fmaxf(lg[mt][nt][0], lg[mt][nt][1]),
                             fmaxf(lg[mt][nt][2], lg[mt][nt][3])));
      cm = fmaxf(cm, __shfl_xor(cm, 16));
      cm = fmaxf(cm, __shfl_xor(cm, 32));
      if (!__all(cm <= mrun[nt] + 8.0f)) {
        const float nm = fmaxf(mrun[nt], cm);
        const float fac = EXP2F(mrun[nt] - nm);
        mrun[nt] = nm;
        lsum[nt] *= fac;
#pragma unroll
        for (int ct = 0; ct < 4; ++ct) acc[ct][nt] *= fac;
      }
    }

    // ---- P = exp2(lg - m); PV in two 32-s halves ----
#pragma unroll
    for (int sh = 0; sh < 2; ++sh) {
#pragma unroll
      for (int mh = 0; mh < 2; ++mh) {
        const int mt = sh * 2 + mh;
#pragma unroll
        for (int nt = 0; nt < 2; ++nt) {
          const int t = nt * 16 + lo;
          f32x4 p;
#pragma unroll
          for (int r = 0; r < 4; ++r) p[r] = EXP2F(lg[mt][nt][r] - mrun[nt]);
          lsum[nt] += (p[0] + p[1]) + (p[2] + p[3]);
          uint2 w;
          w.x = packbf2(p[0], p[1]);
          w.y = packbf2(p[2], p[3]);
          *(uint2*)(Pls + t * 128 + ((mh * 32 + g * 8) ^ ((t & 7) * 16))) = w;
        }
      }
      bf16x8 pb[2];
#pragma unroll
      for (int nt = 0; nt < 2; ++nt) {
        const int t = nt * 16 + lo;
        pb[nt] = *(const bf16x8*)(Pls + t * 128 + ((g * 16) ^ ((t & 7) * 16)));
      }
#pragma unroll
      for (int ct = 0; ct < 4; ++ct) {
        const int cr = ct * 16 + lo;
        const bf16x8 va = *(const bf16x8*)(
            Vls + cr * 128 + ((sh * 64 + g * 16) ^ ((cr & 7) * 16)));
#pragma unroll
        for (int nt = 0; nt < 2; ++nt)
          acc[ct][nt] = __builtin_amdgcn_mfma_f32_16x16x32_bf16(
              va, pb[nt], acc[ct][nt], 0, 0, 0);
      }
    }
  }

  // ---- epilogue: normalize + store ----
#pragma unroll
  for (int nt = 0; nt < 2; ++nt) {
    float s = lsum[nt];
    s += __shfl_xor(s, 16);
    s += __shfl_xor(s, 32);
    const float inv = 1.0f / s;
    const int t = t0 + nt * 16 + lo;
#pragma unroll
    for (int ct = 0; ct < 4; ++ct) {
#pragma unroll
      for (int r = 0; r < 4; ++r) {
        const int c = ct * 16 + g * 4 + r;
        out[((size_t)bh * 64 + c) * 2048 + t] = acc[ct][nt][r] * inv;
      }
    }
  }
}

extern "C" void kernel_launch(void* const* d_in, const int* in_sizes, int n_in,
                              void* d_out, int out_size, void* d_ws,
                              size_t ws_size, hipStream_t stream) {
  (void)in_sizes; (void)n_in; (void)out_size;
  const float* qkv = (const float*)d_in[0];
  float* out = (float*)d_out;
  const size_t kv_elems = (size_t)64 * 2048 * 64;
  if (ws_size < kv_elems * 2 * sizeof(short)) return;  // need 32 MB scratch
  short* Kt = (short*)d_ws;
  short* Vb = Kt + kv_elems;
  hipLaunchKernelGGL(qkv_prep_kernel, dim3(2048), dim3(256), 0, stream,
                     qkv, Kt, Vb);
  hipLaunchKernelGGL(attn32_kernel, dim3(1024), dim3(256), 0, stream,
                     qkv, Kt, Vb, out);
}